// Round 7
// baseline (243.417 us; speedup 1.0000x reference)
//
#include <hip/hip_runtime.h>
#include <math.h>
#include <limits.h>

typedef float nfloat4 __attribute__((ext_vector_type(4)));

// ---------------------------------------------------------------------------
// Kernel 1: updated = x + reco; relu_out = max(updated,0); upd_out = updated.
// R6/R7: one-shot grid, 4 CONSECUTIVE float4 per thread (64 B), all 8 loads
// issued before any store (straight-line unroll) -> 4x the loads in flight
// vs the grid-stride loop (which had 2 and measured 2.74 TB/s / 43% of the
// copy ceiling, VALUBusy 2.2% => MLP-starved, not BW-saturated).
// Evidence: R3's 2x-consecutive batch ran 3.3 TB/s; the FAILED prior-session
// variant strode lanes 2 MB apart (DRAM locality) — consecutive is safe.
// ---------------------------------------------------------------------------
__global__ __launch_bounds__(256) void add_relu_kernel(
    const float* __restrict__ x,
    const float* __restrict__ reco,
    float* __restrict__ relu_out,
    float* __restrict__ upd_out,
    int n4)
{
    const int t = blockIdx.x * blockDim.x + threadIdx.x;
    const int i0 = t * 4;
    const nfloat4* x4 = (const nfloat4*)x;
    const nfloat4* r4 = (const nfloat4*)reco;
    nfloat4* ro4 = (nfloat4*)relu_out;
    nfloat4* uo4 = (nfloat4*)upd_out;

    if (i0 + 3 < n4) {
        // fast path: 8 loads in flight, then 8 stores
        nfloat4 a0 = x4[i0 + 0];
        nfloat4 a1 = x4[i0 + 1];
        nfloat4 a2 = x4[i0 + 2];
        nfloat4 a3 = x4[i0 + 3];
        nfloat4 b0 = r4[i0 + 0];
        nfloat4 b1 = r4[i0 + 1];
        nfloat4 b2 = r4[i0 + 2];
        nfloat4 b3 = r4[i0 + 3];
        nfloat4 u0 = a0 + b0;
        nfloat4 u1 = a1 + b1;
        nfloat4 u2 = a2 + b2;
        nfloat4 u3 = a3 + b3;
        if (uo4) {
            uo4[i0 + 0] = u0;
            uo4[i0 + 1] = u1;
            uo4[i0 + 2] = u2;
            uo4[i0 + 3] = u3;
        }
        nfloat4 r0, r1, r2, r3;
        r0.x = fmaxf(u0.x, 0.f); r0.y = fmaxf(u0.y, 0.f);
        r0.z = fmaxf(u0.z, 0.f); r0.w = fmaxf(u0.w, 0.f);
        r1.x = fmaxf(u1.x, 0.f); r1.y = fmaxf(u1.y, 0.f);
        r1.z = fmaxf(u1.z, 0.f); r1.w = fmaxf(u1.w, 0.f);
        r2.x = fmaxf(u2.x, 0.f); r2.y = fmaxf(u2.y, 0.f);
        r2.z = fmaxf(u2.z, 0.f); r2.w = fmaxf(u2.w, 0.f);
        r3.x = fmaxf(u3.x, 0.f); r3.y = fmaxf(u3.y, 0.f);
        r3.z = fmaxf(u3.z, 0.f); r3.w = fmaxf(u3.w, 0.f);
        ro4[i0 + 0] = r0;
        ro4[i0 + 1] = r1;
        ro4[i0 + 2] = r2;
        ro4[i0 + 3] = r3;
    } else {
        for (int i = i0; i < n4; ++i) {
            nfloat4 a = x4[i];
            nfloat4 b = r4[i];
            nfloat4 u = a + b;
            if (uo4) uo4[i] = u;
            nfloat4 r;
            r.x = fmaxf(u.x, 0.f); r.y = fmaxf(u.y, 0.f);
            r.z = fmaxf(u.z, 0.f); r.w = fmaxf(u.w, 0.f);
            ro4[i] = r;
        }
    }
}

__device__ __forceinline__ void clip_axis(float a, float b, float lo, float hi,
                                          float& t_lo, float& t_hi)
{
    if (fabsf(b) > 1e-6f) {
        float t0 = (lo - a) / b;
        float t1 = (hi - a) / b;
        float tmn = fminf(t0, t1);
        float tmx = fmaxf(t0, t1);
        t_lo = fmaxf(t_lo, tmn);
        t_hi = fminf(t_hi, tmx);
    } else {
        if (a <= lo || a >= hi) { t_lo = 1.0f; t_hi = 0.0f; }
    }
}

// ---------------------------------------------------------------------------
// Generic branchless trilinear sample (per-lane x/y/z). TWO=1 adds vol_b.
// Identical weight products / fmaf chain as all passing rounds.
// ---------------------------------------------------------------------------
template <int TWO>
__device__ __forceinline__ float sample_step(
    const float* __restrict__ vol_a,
    const float* __restrict__ vol_b,
    float s,
    float sx, float sy, float sz,
    float dx, float dy, float dz,
    float inv_sp, float cx, float cy, float cz,
    int nx, int ny, int nz, bool live_step)
{
    const float px = fmaf(s, dx, sx) * inv_sp + cx;
    const float py = fmaf(s, dy, sy) * inv_sp + cy;
    const float pz = fmaf(s, dz, sz) * inv_sp + cz;

    const float x0f = floorf(px);
    const float y0f = floorf(py);
    const float z0f = floorf(pz);
    const float fx = px - x0f;
    const float fy = py - y0f;
    const float fz = pz - z0f;
    const int x0 = (int)x0f;
    const int y0 = (int)y0f;
    const int z0 = (int)z0f;

    const bool vx0 = (unsigned)x0 < (unsigned)nx;
    const bool vx1 = (unsigned)(x0 + 1) < (unsigned)nx;
    const bool vy0 = (unsigned)y0 < (unsigned)ny;
    const bool vy1 = (unsigned)(y0 + 1) < (unsigned)ny;
    const bool vz0 = live_step & ((unsigned)z0 < (unsigned)nz);
    const bool vz1 = live_step & ((unsigned)(z0 + 1) < (unsigned)nz);

    const int xc0 = min(max(x0, 0), nx - 1);
    const int xc1 = min(max(x0 + 1, 0), nx - 1);
    const int yc0 = min(max(y0, 0), ny - 1);
    const int yc1 = min(max(y0 + 1, 0), ny - 1);
    const int zc0 = min(max(z0, 0), nz - 1);
    const int zc1 = min(max(z0 + 1, 0), nz - 1);

    const int r00 = (xc0 * ny + yc0) * nz;
    const int r01 = (xc0 * ny + yc1) * nz;
    const int r10 = (xc1 * ny + yc0) * nz;
    const int r11 = (xc1 * ny + yc1) * nz;

    float v000 = vol_a[r00 + zc0];
    float v001 = vol_a[r00 + zc1];
    float v010 = vol_a[r01 + zc0];
    float v011 = vol_a[r01 + zc1];
    float v100 = vol_a[r10 + zc0];
    float v101 = vol_a[r10 + zc1];
    float v110 = vol_a[r11 + zc0];
    float v111 = vol_a[r11 + zc1];
    if (TWO) {
        v000 += vol_b[r00 + zc0];
        v001 += vol_b[r00 + zc1];
        v010 += vol_b[r01 + zc0];
        v011 += vol_b[r01 + zc1];
        v100 += vol_b[r10 + zc0];
        v101 += vol_b[r10 + zc1];
        v110 += vol_b[r11 + zc0];
        v111 += vol_b[r11 + zc1];
    }

    const float gx = 1.0f - fx;
    const float gy = 1.0f - fy;
    const float gz = 1.0f - fz;
    const float wxy00 = gx * gy;
    const float wxy01 = gx * fy;
    const float wxy10 = fx * gy;
    const float wxy11 = fx * fy;

    const float w000 = (vx0 & vy0 & vz0) ? wxy00 * gz : 0.0f;
    const float w001 = (vx0 & vy0 & vz1) ? wxy00 * fz : 0.0f;
    const float w010 = (vx0 & vy1 & vz0) ? wxy01 * gz : 0.0f;
    const float w011 = (vx0 & vy1 & vz1) ? wxy01 * fz : 0.0f;
    const float w100 = (vx1 & vy0 & vz0) ? wxy10 * gz : 0.0f;
    const float w101 = (vx1 & vy0 & vz1) ? wxy10 * fz : 0.0f;
    const float w110 = (vx1 & vy1 & vz0) ? wxy11 * gz : 0.0f;
    const float w111 = (vx1 & vy1 & vz1) ? wxy11 * fz : 0.0f;

    float samp = 0.0f;
    samp = fmaf(w000, v000, samp);
    samp = fmaf(w001, v001, samp);
    samp = fmaf(w010, v010, samp);
    samp = fmaf(w011, v011, samp);
    samp = fmaf(w100, v100, samp);
    samp = fmaf(w101, v101, samp);
    samp = fmaf(w110, v110, samp);
    samp = fmaf(w111, v111, samp);
    return samp;
}

// ---------------------------------------------------------------------------
// x/y-SCALARIZED sample. PRECONDITION (enforced by caller): s is bit-uniform
// across the wave (loop bounds wave-reduced) AND det_v_vec.xy == 0 with
// lanes sharing (view,u) => px,py bit-uniform => readfirstlane is identity.
// ---------------------------------------------------------------------------
__device__ __forceinline__ float sample_step_u(
    const float* __restrict__ vol,
    float s,
    float sx, float sy, float sz,
    float dx, float dy, float dz,
    float inv_sp, float cx, float cy, float cz,
    int nx, int ny, int nz, bool live_step)
{
    const float px = fmaf(s, dx, sx) * inv_sp + cx;
    const float py = fmaf(s, dy, sy) * inv_sp + cy;
    const float pz = fmaf(s, dz, sz) * inv_sp + cz;

    const float x0f = floorf(px);
    const float y0f = floorf(py);
    const float z0f = floorf(pz);
    const float fx = px - x0f;
    const float fy = py - y0f;
    const float fz = pz - z0f;
    const int x0 = __builtin_amdgcn_readfirstlane((int)x0f);
    const int y0 = __builtin_amdgcn_readfirstlane((int)y0f);
    const int z0 = (int)z0f;

    const bool vx0 = (unsigned)x0 < (unsigned)nx;          // scalar
    const bool vx1 = (unsigned)(x0 + 1) < (unsigned)nx;    // scalar
    const bool vy0 = (unsigned)y0 < (unsigned)ny;          // scalar
    const bool vy1 = (unsigned)(y0 + 1) < (unsigned)ny;    // scalar
    const bool vz0 = live_step & ((unsigned)z0 < (unsigned)nz);
    const bool vz1 = live_step & ((unsigned)(z0 + 1) < (unsigned)nz);

    const int xc0 = min(max(x0, 0), nx - 1);               // scalar
    const int xc1 = min(max(x0 + 1, 0), nx - 1);
    const int yc0 = min(max(y0, 0), ny - 1);
    const int yc1 = min(max(y0 + 1, 0), ny - 1);
    const int zc0 = min(max(z0, 0), nz - 1);               // per-lane
    const int zc1 = min(max(z0 + 1, 0), nz - 1);

    const float* row00 = vol + (xc0 * ny + yc0) * nz;      // scalar bases
    const float* row01 = vol + (xc0 * ny + yc1) * nz;
    const float* row10 = vol + (xc1 * ny + yc0) * nz;
    const float* row11 = vol + (xc1 * ny + yc1) * nz;

    const float v000 = row00[zc0];
    const float v001 = row00[zc1];
    const float v010 = row01[zc0];
    const float v011 = row01[zc1];
    const float v100 = row10[zc0];
    const float v101 = row10[zc1];
    const float v110 = row11[zc0];
    const float v111 = row11[zc1];

    const float gx = 1.0f - fx;
    const float gy = 1.0f - fy;
    const float gz = 1.0f - fz;
    const float wxy00 = gx * gy;
    const float wxy01 = gx * fy;
    const float wxy10 = fx * gy;
    const float wxy11 = fx * fy;

    const float w000 = (vx0 & vy0 & vz0) ? wxy00 * gz : 0.0f;
    const float w001 = (vx0 & vy0 & vz1) ? wxy00 * fz : 0.0f;
    const float w010 = (vx0 & vy1 & vz0) ? wxy01 * gz : 0.0f;
    const float w011 = (vx0 & vy1 & vz1) ? wxy01 * fz : 0.0f;
    const float w100 = (vx1 & vy0 & vz0) ? wxy10 * gz : 0.0f;
    const float w101 = (vx1 & vy0 & vz1) ? wxy10 * fz : 0.0f;
    const float w110 = (vx1 & vy1 & vz0) ? wxy11 * gz : 0.0f;
    const float w111 = (vx1 & vy1 & vz1) ? wxy11 * fz : 0.0f;

    float samp = 0.0f;
    samp = fmaf(w000, v000, samp);
    samp = fmaf(w001, v001, samp);
    samp = fmaf(w010, v010, samp);
    samp = fmaf(w011, v011, samp);
    samp = fmaf(w100, v100, samp);
    samp = fmaf(w101, v101, samp);
    samp = fmaf(w110, v110, samp);
    samp = fmaf(w111, v111, samp);
    return samp;
}

// ---------------------------------------------------------------------------
// Kernel 2: cone projection — UNCHANGED from R5 (passed, absmax 0.031).
// Staged single volume, serial after add_relu (R2/R3: co-run and dual-read
// both regress). 64 consecutive-v pixels x 4 waves x {seg,seg+4} chains.
// Scalarized x/y path gated on (det_v%64==0 && det_v_vec.xy==0) with
// WAVE-UNIFORM step bounds (R4 bugfix).
// ---------------------------------------------------------------------------
template <int TWO>
__global__ __launch_bounds__(256, 4) void cone_project_seg_kernel(
    const float* __restrict__ vol_a,
    const float* __restrict__ vol_b,
    const float* __restrict__ src_pos,
    const float* __restrict__ det_center,
    const float* __restrict__ det_u_vec,
    const float* __restrict__ det_v_vec,
    const float* __restrict__ du_p,
    const float* __restrict__ dv_p,
    const float* __restrict__ spacing_p,
    const int* __restrict__ det_u_p,
    const int* __restrict__ det_v_p,
    const int* __restrict__ nsteps_p,
    float* __restrict__ sino,
    int n_views, int nx, int ny, int nz)
{
    const int det_u = *det_u_p;
    const int det_v = *det_v_p;
    const int n_steps = *nsteps_p;
    const float du = *du_p;
    const float dv = *dv_p;
    const float inv_sp = 1.0f / *spacing_p;

    const long total = (long)n_views * det_u * det_v;
    const int pix = threadIdx.x & 63;   // lane: consecutive v
    const int seg = threadIdx.x >> 6;   // wave id: 0..3

    int bid = blockIdx.x;
    if ((gridDim.x & 7) == 0) {
        const int cpx = (int)(gridDim.x >> 3);
        bid = (bid & 7) * cpx + (bid >> 3);
    }

    const long idx = (long)bid * 64 + pix;
    const bool live = idx < total;

    const long cidx = live ? idx : 0;
    const int v = (int)(cidx % det_v);
    const int u = (int)((cidx / det_v) % det_u);
    const int view = (int)(cidx / ((long)det_u * det_v));

    const float us = ((float)u - (det_u - 1) * 0.5f) * du;
    const float vs = ((float)v - (det_v - 1) * 0.5f) * dv;

    const float sx = src_pos[view * 3 + 0];
    const float sy = src_pos[view * 3 + 1];
    const float sz = src_pos[view * 3 + 2];

    const float dvx = det_v_vec[view * 3 + 0];
    const float dvy = det_v_vec[view * 3 + 1];
    const float dvz = det_v_vec[view * 3 + 2];

    const float dpx = det_center[view * 3 + 0] + us * det_u_vec[view * 3 + 0] + vs * dvx;
    const float dpy = det_center[view * 3 + 1] + us * det_u_vec[view * 3 + 1] + vs * dvy;
    const float dpz = det_center[view * 3 + 2] + us * det_u_vec[view * 3 + 2] + vs * dvz;

    const float dx = dpx - sx;
    const float dy = dpy - sy;
    const float dz = dpz - sz;
    const float ray_len = sqrtf(dx * dx + dy * dy + dz * dz);
    const float step_len = ray_len / (float)n_steps;

    const float cx = (nx - 1) * 0.5f;
    const float cy = (ny - 1) * 0.5f;
    const float cz = (nz - 1) * 0.5f;

    float t_lo = 0.0f, t_hi = 1.0f;
    clip_axis(sx * inv_sp + cx, dx * inv_sp, -1.0f, (float)nx, t_lo, t_hi);
    clip_axis(sy * inv_sp + cy, dy * inv_sp, -1.0f, (float)ny, t_lo, t_hi);
    clip_axis(sz * inv_sp + cz, dz * inv_sp, -1.0f, (float)nz, t_lo, t_hi);

    int i_min = 0, i_max = -1;
    if (t_hi > t_lo) {
        i_min = (int)floorf(t_lo * (float)n_steps - 0.5f) - 1;
        i_max = (int)ceilf(t_hi * (float)n_steps - 0.5f) + 1;
        i_min = max(i_min, 0);
        i_max = min(i_max, n_steps - 1);
    }
    if (!live) { i_min = 0; i_max = -1; }

    const float inv_n = 1.0f / (float)n_steps;
    float accA = 0.0f;
    float accB = 0.0f;

    const bool uniform_ok = !TWO && ((det_v & 63) == 0) &&
                            (dvx == 0.0f) && (dvy == 0.0f);

    if (uniform_ok) {
        // ---- wave-uniform step bounds (R4 bugfix) ----
        int lo = (i_max < i_min) ? INT_MAX : i_min;   // sentinel for miss rays
        int hi = (i_max < i_min) ? INT_MIN : i_max;
        for (int m = 1; m < 64; m <<= 1) {
            lo = min(lo, __shfl_xor(lo, m));
            hi = max(hi, __shfl_xor(hi, m));
        }
        if (hi < lo) { lo = 0; hi = -1; }             // whole wave missed

        const int count = hi - lo + 1;
        const int per8 = (count + 7) >> 3;
        const int isA = lo + seg * per8;
        const int isB = lo + (seg + 4) * per8;
        const int ieA = min(isA + per8 - 1, hi);
        const int ieB = min(isB + per8 - 1, hi);

        for (int j = 0; j < per8; ++j) {
            const int iA = isA + j;
            const int iB = isB + j;
            const float sA = ((float)iA + 0.5f) * inv_n;
            const float sB = ((float)iB + 0.5f) * inv_n;
            accA += sample_step_u(vol_a, sA, sx, sy, sz, dx, dy, dz,
                                  inv_sp, cx, cy, cz, nx, ny, nz, iA <= ieA);
            accB += sample_step_u(vol_a, sB, sx, sy, sz, dx, dy, dz,
                                  inv_sp, cx, cy, cz, nx, ny, nz, iB <= ieB);
        }
    } else {
        const int count = i_max - i_min + 1;
        const int per8 = (count + 7) >> 3;
        const int isA = i_min + seg * per8;
        const int isB = i_min + (seg + 4) * per8;
        const int ieA = min(isA + per8 - 1, i_max);
        const int ieB = min(isB + per8 - 1, i_max);

        for (int j = 0; j < per8; ++j) {
            const int iA = isA + j;
            const int iB = isB + j;
            const float sA = ((float)iA + 0.5f) * inv_n;
            const float sB = ((float)iB + 0.5f) * inv_n;
            accA += sample_step<TWO>(vol_a, vol_b, sA, sx, sy, sz, dx, dy, dz,
                                     inv_sp, cx, cy, cz, nx, ny, nz, iA <= ieA);
            accB += sample_step<TWO>(vol_a, vol_b, sB, sx, sy, sz, dx, dy, dz,
                                     inv_sp, cx, cy, cz, nx, ny, nz, iB <= ieB);
        }
    }
    const float acc = accA + accB;

    __shared__ float red[256];
    red[threadIdx.x] = acc;
    __syncthreads();
    if (seg == 0 && live) {
        float tot = red[pix] + red[pix + 64] + red[pix + 128] + red[pix + 192];
        sino[idx] = tot * step_len;
    }
}

extern "C" void kernel_launch(void* const* d_in, const int* in_sizes, int n_in,
                              void* d_out, int out_size, void* d_ws, size_t ws_size,
                              hipStream_t stream) {
    const float* x          = (const float*)d_in[0];
    const float* reco       = (const float*)d_in[1];
    const float* src_pos    = (const float*)d_in[2];
    const float* det_center = (const float*)d_in[3];
    const float* det_u_vec  = (const float*)d_in[4];
    const float* det_v_vec  = (const float*)d_in[5];
    const float* du_p       = (const float*)d_in[6];
    const float* dv_p       = (const float*)d_in[7];
    const float* spacing_p  = (const float*)d_in[8];
    const int*   det_u_p    = (const int*)d_in[9];
    const int*   det_v_p    = (const int*)d_in[10];
    const int*   nsteps_p   = (const int*)d_in[11];

    const int n_vol = in_sizes[0];          // 256^3
    const int n_views = in_sizes[2] / 3;    // 8

    int n = 1;
    while ((long)(n + 1) * (n + 1) * (n + 1) <= (long)n_vol) ++n;
    const int nx = n, ny = n, nz = n;

    const int sino_size = out_size - n_vol;  // 8*128*128
    float* sino     = (float*)d_out;
    float* relu_out = (float*)d_out + sino_size;

    const bool use_ws = ws_size >= (size_t)n_vol * sizeof(float);
    float* upd = (float*)d_ws;

    // --- Pass 1: elementwise add + relu (+ stage updated volume) ---
    const int n4 = n_vol / 4;
    const int add_blocks = (n4 / 4 + 255) / 256;   // 4096 for 256^3
    add_relu_kernel<<<add_blocks, 256, 0, stream>>>(
        x, reco, relu_out, use_ws ? upd : nullptr, n4);

    // --- Pass 2: cone projection (staged volume, L3-warm from pass 1) ---
    const int blocks = (sino_size + 63) / 64;
    if (use_ws) {
        cone_project_seg_kernel<0><<<blocks, 256, 0, stream>>>(
            upd, nullptr,
            src_pos, det_center, det_u_vec, det_v_vec,
            du_p, dv_p, spacing_p, det_u_p, det_v_p, nsteps_p,
            sino, n_views, nx, ny, nz);
    } else {
        cone_project_seg_kernel<1><<<blocks, 256, 0, stream>>>(
            x, reco,
            src_pos, det_center, det_u_vec, det_v_vec,
            du_p, dv_p, spacing_p, det_u_p, det_v_p, nsteps_p,
            sino, n_views, nx, ny, nz);
    }
}

// Round 8
// 234.918 us; speedup vs baseline: 1.0362x; 1.0362x over previous
//
#include <hip/hip_runtime.h>
#include <math.h>
#include <limits.h>

typedef float nfloat4 __attribute__((ext_vector_type(4)));

// ---------------------------------------------------------------------------
// Kernel 1: updated = x + reco; relu_out = max(updated,0); upd_out = updated.
// R8: INTERLEAVED 4x batch. R7 proved blocked-per-thread batching (i0=t*4)
// regresses (83 us, 2.43 TB/s): each load instruction had lanes 64 B apart
// -> 1/4 cache-line utilization per instruction. Here thread t handles
// base+t+k*256 (k=0..3): every load/store instruction is 64 lanes x 16 B
// CONTIGUOUS (same per-instruction pattern as the 73 us grid-stride loop)
// while still holding 8 loads in flight before any store (MLP).
// ---------------------------------------------------------------------------
__global__ __launch_bounds__(256) void add_relu_kernel(
    const float* __restrict__ x,
    const float* __restrict__ reco,
    float* __restrict__ relu_out,
    float* __restrict__ upd_out,
    int n4)
{
    const int base = blockIdx.x * (blockDim.x * 4) + threadIdx.x;
    const nfloat4* x4 = (const nfloat4*)x;
    const nfloat4* r4 = (const nfloat4*)reco;
    nfloat4* ro4 = (nfloat4*)relu_out;
    nfloat4* uo4 = (nfloat4*)upd_out;

    const int i0 = base;
    const int i1 = base + 256;
    const int i2 = base + 512;
    const int i3 = base + 768;

    if (i3 < n4) {
        // fast path: 8 coalesced loads in flight, then stores
        nfloat4 a0 = x4[i0];
        nfloat4 a1 = x4[i1];
        nfloat4 a2 = x4[i2];
        nfloat4 a3 = x4[i3];
        nfloat4 b0 = r4[i0];
        nfloat4 b1 = r4[i1];
        nfloat4 b2 = r4[i2];
        nfloat4 b3 = r4[i3];
        nfloat4 u0 = a0 + b0;
        nfloat4 u1 = a1 + b1;
        nfloat4 u2 = a2 + b2;
        nfloat4 u3 = a3 + b3;
        if (uo4) {
            uo4[i0] = u0;
            uo4[i1] = u1;
            uo4[i2] = u2;
            uo4[i3] = u3;
        }
        nfloat4 r0, r1, r2, r3;
        r0.x = fmaxf(u0.x, 0.f); r0.y = fmaxf(u0.y, 0.f);
        r0.z = fmaxf(u0.z, 0.f); r0.w = fmaxf(u0.w, 0.f);
        r1.x = fmaxf(u1.x, 0.f); r1.y = fmaxf(u1.y, 0.f);
        r1.z = fmaxf(u1.z, 0.f); r1.w = fmaxf(u1.w, 0.f);
        r2.x = fmaxf(u2.x, 0.f); r2.y = fmaxf(u2.y, 0.f);
        r2.z = fmaxf(u2.z, 0.f); r2.w = fmaxf(u2.w, 0.f);
        r3.x = fmaxf(u3.x, 0.f); r3.y = fmaxf(u3.y, 0.f);
        r3.z = fmaxf(u3.z, 0.f); r3.w = fmaxf(u3.w, 0.f);
        ro4[i0] = r0;
        ro4[i1] = r1;
        ro4[i2] = r2;
        ro4[i3] = r3;
    } else {
        // tail: per-element, still coalesced
        for (int k = 0; k < 4; ++k) {
            const int i = base + k * 256;
            if (i < n4) {
                nfloat4 a = x4[i];
                nfloat4 b = r4[i];
                nfloat4 u = a + b;
                if (uo4) uo4[i] = u;
                nfloat4 r;
                r.x = fmaxf(u.x, 0.f); r.y = fmaxf(u.y, 0.f);
                r.z = fmaxf(u.z, 0.f); r.w = fmaxf(u.w, 0.f);
                ro4[i] = r;
            }
        }
    }
}

__device__ __forceinline__ void clip_axis(float a, float b, float lo, float hi,
                                          float& t_lo, float& t_hi)
{
    if (fabsf(b) > 1e-6f) {
        float t0 = (lo - a) / b;
        float t1 = (hi - a) / b;
        float tmn = fminf(t0, t1);
        float tmx = fmaxf(t0, t1);
        t_lo = fmaxf(t_lo, tmn);
        t_hi = fminf(t_hi, tmx);
    } else {
        if (a <= lo || a >= hi) { t_lo = 1.0f; t_hi = 0.0f; }
    }
}

// ---------------------------------------------------------------------------
// Generic branchless trilinear sample (per-lane x/y/z). TWO=1 adds vol_b.
// Identical weight products / fmaf chain as all passing rounds.
// ---------------------------------------------------------------------------
template <int TWO>
__device__ __forceinline__ float sample_step(
    const float* __restrict__ vol_a,
    const float* __restrict__ vol_b,
    float s,
    float sx, float sy, float sz,
    float dx, float dy, float dz,
    float inv_sp, float cx, float cy, float cz,
    int nx, int ny, int nz, bool live_step)
{
    const float px = fmaf(s, dx, sx) * inv_sp + cx;
    const float py = fmaf(s, dy, sy) * inv_sp + cy;
    const float pz = fmaf(s, dz, sz) * inv_sp + cz;

    const float x0f = floorf(px);
    const float y0f = floorf(py);
    const float z0f = floorf(pz);
    const float fx = px - x0f;
    const float fy = py - y0f;
    const float fz = pz - z0f;
    const int x0 = (int)x0f;
    const int y0 = (int)y0f;
    const int z0 = (int)z0f;

    const bool vx0 = (unsigned)x0 < (unsigned)nx;
    const bool vx1 = (unsigned)(x0 + 1) < (unsigned)nx;
    const bool vy0 = (unsigned)y0 < (unsigned)ny;
    const bool vy1 = (unsigned)(y0 + 1) < (unsigned)ny;
    const bool vz0 = live_step & ((unsigned)z0 < (unsigned)nz);
    const bool vz1 = live_step & ((unsigned)(z0 + 1) < (unsigned)nz);

    const int xc0 = min(max(x0, 0), nx - 1);
    const int xc1 = min(max(x0 + 1, 0), nx - 1);
    const int yc0 = min(max(y0, 0), ny - 1);
    const int yc1 = min(max(y0 + 1, 0), ny - 1);
    const int zc0 = min(max(z0, 0), nz - 1);
    const int zc1 = min(max(z0 + 1, 0), nz - 1);

    const int r00 = (xc0 * ny + yc0) * nz;
    const int r01 = (xc0 * ny + yc1) * nz;
    const int r10 = (xc1 * ny + yc0) * nz;
    const int r11 = (xc1 * ny + yc1) * nz;

    float v000 = vol_a[r00 + zc0];
    float v001 = vol_a[r00 + zc1];
    float v010 = vol_a[r01 + zc0];
    float v011 = vol_a[r01 + zc1];
    float v100 = vol_a[r10 + zc0];
    float v101 = vol_a[r10 + zc1];
    float v110 = vol_a[r11 + zc0];
    float v111 = vol_a[r11 + zc1];
    if (TWO) {
        v000 += vol_b[r00 + zc0];
        v001 += vol_b[r00 + zc1];
        v010 += vol_b[r01 + zc0];
        v011 += vol_b[r01 + zc1];
        v100 += vol_b[r10 + zc0];
        v101 += vol_b[r10 + zc1];
        v110 += vol_b[r11 + zc0];
        v111 += vol_b[r11 + zc1];
    }

    const float gx = 1.0f - fx;
    const float gy = 1.0f - fy;
    const float gz = 1.0f - fz;
    const float wxy00 = gx * gy;
    const float wxy01 = gx * fy;
    const float wxy10 = fx * gy;
    const float wxy11 = fx * fy;

    const float w000 = (vx0 & vy0 & vz0) ? wxy00 * gz : 0.0f;
    const float w001 = (vx0 & vy0 & vz1) ? wxy00 * fz : 0.0f;
    const float w010 = (vx0 & vy1 & vz0) ? wxy01 * gz : 0.0f;
    const float w011 = (vx0 & vy1 & vz1) ? wxy01 * fz : 0.0f;
    const float w100 = (vx1 & vy0 & vz0) ? wxy10 * gz : 0.0f;
    const float w101 = (vx1 & vy0 & vz1) ? wxy10 * fz : 0.0f;
    const float w110 = (vx1 & vy1 & vz0) ? wxy11 * gz : 0.0f;
    const float w111 = (vx1 & vy1 & vz1) ? wxy11 * fz : 0.0f;

    float samp = 0.0f;
    samp = fmaf(w000, v000, samp);
    samp = fmaf(w001, v001, samp);
    samp = fmaf(w010, v010, samp);
    samp = fmaf(w011, v011, samp);
    samp = fmaf(w100, v100, samp);
    samp = fmaf(w101, v101, samp);
    samp = fmaf(w110, v110, samp);
    samp = fmaf(w111, v111, samp);
    return samp;
}

// ---------------------------------------------------------------------------
// x/y-SCALARIZED sample. PRECONDITION (enforced by caller): s is bit-uniform
// across the wave (loop bounds wave-reduced) AND det_v_vec.xy == 0 with
// lanes sharing (view,u) => px,py bit-uniform => readfirstlane is identity.
// ---------------------------------------------------------------------------
__device__ __forceinline__ float sample_step_u(
    const float* __restrict__ vol,
    float s,
    float sx, float sy, float sz,
    float dx, float dy, float dz,
    float inv_sp, float cx, float cy, float cz,
    int nx, int ny, int nz, bool live_step)
{
    const float px = fmaf(s, dx, sx) * inv_sp + cx;
    const float py = fmaf(s, dy, sy) * inv_sp + cy;
    const float pz = fmaf(s, dz, sz) * inv_sp + cz;

    const float x0f = floorf(px);
    const float y0f = floorf(py);
    const float z0f = floorf(pz);
    const float fx = px - x0f;
    const float fy = py - y0f;
    const float fz = pz - z0f;
    const int x0 = __builtin_amdgcn_readfirstlane((int)x0f);
    const int y0 = __builtin_amdgcn_readfirstlane((int)y0f);
    const int z0 = (int)z0f;

    const bool vx0 = (unsigned)x0 < (unsigned)nx;          // scalar
    const bool vx1 = (unsigned)(x0 + 1) < (unsigned)nx;    // scalar
    const bool vy0 = (unsigned)y0 < (unsigned)ny;          // scalar
    const bool vy1 = (unsigned)(y0 + 1) < (unsigned)ny;    // scalar
    const bool vz0 = live_step & ((unsigned)z0 < (unsigned)nz);
    const bool vz1 = live_step & ((unsigned)(z0 + 1) < (unsigned)nz);

    const int xc0 = min(max(x0, 0), nx - 1);               // scalar
    const int xc1 = min(max(x0 + 1, 0), nx - 1);
    const int yc0 = min(max(y0, 0), ny - 1);
    const int yc1 = min(max(y0 + 1, 0), ny - 1);
    const int zc0 = min(max(z0, 0), nz - 1);               // per-lane
    const int zc1 = min(max(z0 + 1, 0), nz - 1);

    const float* row00 = vol + (xc0 * ny + yc0) * nz;      // scalar bases
    const float* row01 = vol + (xc0 * ny + yc1) * nz;
    const float* row10 = vol + (xc1 * ny + yc0) * nz;
    const float* row11 = vol + (xc1 * ny + yc1) * nz;

    const float v000 = row00[zc0];
    const float v001 = row00[zc1];
    const float v010 = row01[zc0];
    const float v011 = row01[zc1];
    const float v100 = row10[zc0];
    const float v101 = row10[zc1];
    const float v110 = row11[zc0];
    const float v111 = row11[zc1];

    const float gx = 1.0f - fx;
    const float gy = 1.0f - fy;
    const float gz = 1.0f - fz;
    const float wxy00 = gx * gy;
    const float wxy01 = gx * fy;
    const float wxy10 = fx * gy;
    const float wxy11 = fx * fy;

    const float w000 = (vx0 & vy0 & vz0) ? wxy00 * gz : 0.0f;
    const float w001 = (vx0 & vy0 & vz1) ? wxy00 * fz : 0.0f;
    const float w010 = (vx0 & vy1 & vz0) ? wxy01 * gz : 0.0f;
    const float w011 = (vx0 & vy1 & vz1) ? wxy01 * fz : 0.0f;
    const float w100 = (vx1 & vy0 & vz0) ? wxy10 * gz : 0.0f;
    const float w101 = (vx1 & vy0 & vz1) ? wxy10 * fz : 0.0f;
    const float w110 = (vx1 & vy1 & vz0) ? wxy11 * gz : 0.0f;
    const float w111 = (vx1 & vy1 & vz1) ? wxy11 * fz : 0.0f;

    float samp = 0.0f;
    samp = fmaf(w000, v000, samp);
    samp = fmaf(w001, v001, samp);
    samp = fmaf(w010, v010, samp);
    samp = fmaf(w011, v011, samp);
    samp = fmaf(w100, v100, samp);
    samp = fmaf(w101, v101, samp);
    samp = fmaf(w110, v110, samp);
    samp = fmaf(w111, v111, samp);
    return samp;
}

// ---------------------------------------------------------------------------
// Kernel 2: cone projection — UNCHANGED from R5 (passed, absmax 0.031).
// Staged single volume, serial after add_relu (R2/R3: co-run and dual-read
// both regress). 64 consecutive-v pixels x 4 waves x {seg,seg+4} chains.
// Scalarized x/y path gated on (det_v%64==0 && det_v_vec.xy==0) with
// WAVE-UNIFORM step bounds (R4 bugfix).
// ---------------------------------------------------------------------------
template <int TWO>
__global__ __launch_bounds__(256, 4) void cone_project_seg_kernel(
    const float* __restrict__ vol_a,
    const float* __restrict__ vol_b,
    const float* __restrict__ src_pos,
    const float* __restrict__ det_center,
    const float* __restrict__ det_u_vec,
    const float* __restrict__ det_v_vec,
    const float* __restrict__ du_p,
    const float* __restrict__ dv_p,
    const float* __restrict__ spacing_p,
    const int* __restrict__ det_u_p,
    const int* __restrict__ det_v_p,
    const int* __restrict__ nsteps_p,
    float* __restrict__ sino,
    int n_views, int nx, int ny, int nz)
{
    const int det_u = *det_u_p;
    const int det_v = *det_v_p;
    const int n_steps = *nsteps_p;
    const float du = *du_p;
    const float dv = *dv_p;
    const float inv_sp = 1.0f / *spacing_p;

    const long total = (long)n_views * det_u * det_v;
    const int pix = threadIdx.x & 63;   // lane: consecutive v
    const int seg = threadIdx.x >> 6;   // wave id: 0..3

    int bid = blockIdx.x;
    if ((gridDim.x & 7) == 0) {
        const int cpx = (int)(gridDim.x >> 3);
        bid = (bid & 7) * cpx + (bid >> 3);
    }

    const long idx = (long)bid * 64 + pix;
    const bool live = idx < total;

    const long cidx = live ? idx : 0;
    const int v = (int)(cidx % det_v);
    const int u = (int)((cidx / det_v) % det_u);
    const int view = (int)(cidx / ((long)det_u * det_v));

    const float us = ((float)u - (det_u - 1) * 0.5f) * du;
    const float vs = ((float)v - (det_v - 1) * 0.5f) * dv;

    const float sx = src_pos[view * 3 + 0];
    const float sy = src_pos[view * 3 + 1];
    const float sz = src_pos[view * 3 + 2];

    const float dvx = det_v_vec[view * 3 + 0];
    const float dvy = det_v_vec[view * 3 + 1];
    const float dvz = det_v_vec[view * 3 + 2];

    const float dpx = det_center[view * 3 + 0] + us * det_u_vec[view * 3 + 0] + vs * dvx;
    const float dpy = det_center[view * 3 + 1] + us * det_u_vec[view * 3 + 1] + vs * dvy;
    const float dpz = det_center[view * 3 + 2] + us * det_u_vec[view * 3 + 2] + vs * dvz;

    const float dx = dpx - sx;
    const float dy = dpy - sy;
    const float dz = dpz - sz;
    const float ray_len = sqrtf(dx * dx + dy * dy + dz * dz);
    const float step_len = ray_len / (float)n_steps;

    const float cx = (nx - 1) * 0.5f;
    const float cy = (ny - 1) * 0.5f;
    const float cz = (nz - 1) * 0.5f;

    float t_lo = 0.0f, t_hi = 1.0f;
    clip_axis(sx * inv_sp + cx, dx * inv_sp, -1.0f, (float)nx, t_lo, t_hi);
    clip_axis(sy * inv_sp + cy, dy * inv_sp, -1.0f, (float)ny, t_lo, t_hi);
    clip_axis(sz * inv_sp + cz, dz * inv_sp, -1.0f, (float)nz, t_lo, t_hi);

    int i_min = 0, i_max = -1;
    if (t_hi > t_lo) {
        i_min = (int)floorf(t_lo * (float)n_steps - 0.5f) - 1;
        i_max = (int)ceilf(t_hi * (float)n_steps - 0.5f) + 1;
        i_min = max(i_min, 0);
        i_max = min(i_max, n_steps - 1);
    }
    if (!live) { i_min = 0; i_max = -1; }

    const float inv_n = 1.0f / (float)n_steps;
    float accA = 0.0f;
    float accB = 0.0f;

    const bool uniform_ok = !TWO && ((det_v & 63) == 0) &&
                            (dvx == 0.0f) && (dvy == 0.0f);

    if (uniform_ok) {
        // ---- wave-uniform step bounds (R4 bugfix) ----
        int lo = (i_max < i_min) ? INT_MAX : i_min;   // sentinel for miss rays
        int hi = (i_max < i_min) ? INT_MIN : i_max;
        for (int m = 1; m < 64; m <<= 1) {
            lo = min(lo, __shfl_xor(lo, m));
            hi = max(hi, __shfl_xor(hi, m));
        }
        if (hi < lo) { lo = 0; hi = -1; }             // whole wave missed

        const int count = hi - lo + 1;
        const int per8 = (count + 7) >> 3;
        const int isA = lo + seg * per8;
        const int isB = lo + (seg + 4) * per8;
        const int ieA = min(isA + per8 - 1, hi);
        const int ieB = min(isB + per8 - 1, hi);

        for (int j = 0; j < per8; ++j) {
            const int iA = isA + j;
            const int iB = isB + j;
            const float sA = ((float)iA + 0.5f) * inv_n;
            const float sB = ((float)iB + 0.5f) * inv_n;
            accA += sample_step_u(vol_a, sA, sx, sy, sz, dx, dy, dz,
                                  inv_sp, cx, cy, cz, nx, ny, nz, iA <= ieA);
            accB += sample_step_u(vol_a, sB, sx, sy, sz, dx, dy, dz,
                                  inv_sp, cx, cy, cz, nx, ny, nz, iB <= ieB);
        }
    } else {
        const int count = i_max - i_min + 1;
        const int per8 = (count + 7) >> 3;
        const int isA = i_min + seg * per8;
        const int isB = i_min + (seg + 4) * per8;
        const int ieA = min(isA + per8 - 1, i_max);
        const int ieB = min(isB + per8 - 1, i_max);

        for (int j = 0; j < per8; ++j) {
            const int iA = isA + j;
            const int iB = isB + j;
            const float sA = ((float)iA + 0.5f) * inv_n;
            const float sB = ((float)iB + 0.5f) * inv_n;
            accA += sample_step<TWO>(vol_a, vol_b, sA, sx, sy, sz, dx, dy, dz,
                                     inv_sp, cx, cy, cz, nx, ny, nz, iA <= ieA);
            accB += sample_step<TWO>(vol_a, vol_b, sB, sx, sy, sz, dx, dy, dz,
                                     inv_sp, cx, cy, cz, nx, ny, nz, iB <= ieB);
        }
    }
    const float acc = accA + accB;

    __shared__ float red[256];
    red[threadIdx.x] = acc;
    __syncthreads();
    if (seg == 0 && live) {
        float tot = red[pix] + red[pix + 64] + red[pix + 128] + red[pix + 192];
        sino[idx] = tot * step_len;
    }
}

extern "C" void kernel_launch(void* const* d_in, const int* in_sizes, int n_in,
                              void* d_out, int out_size, void* d_ws, size_t ws_size,
                              hipStream_t stream) {
    const float* x          = (const float*)d_in[0];
    const float* reco       = (const float*)d_in[1];
    const float* src_pos    = (const float*)d_in[2];
    const float* det_center = (const float*)d_in[3];
    const float* det_u_vec  = (const float*)d_in[4];
    const float* det_v_vec  = (const float*)d_in[5];
    const float* du_p       = (const float*)d_in[6];
    const float* dv_p       = (const float*)d_in[7];
    const float* spacing_p  = (const float*)d_in[8];
    const int*   det_u_p    = (const int*)d_in[9];
    const int*   det_v_p    = (const int*)d_in[10];
    const int*   nsteps_p   = (const int*)d_in[11];

    const int n_vol = in_sizes[0];          // 256^3
    const int n_views = in_sizes[2] / 3;    // 8

    int n = 1;
    while ((long)(n + 1) * (n + 1) * (n + 1) <= (long)n_vol) ++n;
    const int nx = n, ny = n, nz = n;

    const int sino_size = out_size - n_vol;  // 8*128*128
    float* sino     = (float*)d_out;
    float* relu_out = (float*)d_out + sino_size;

    const bool use_ws = ws_size >= (size_t)n_vol * sizeof(float);
    float* upd = (float*)d_ws;

    // --- Pass 1: elementwise add + relu (+ stage updated volume) ---
    const int n4 = n_vol / 4;
    const int add_blocks = (n4 + 1023) / 1024;   // 4096 for 256^3
    add_relu_kernel<<<add_blocks, 256, 0, stream>>>(
        x, reco, relu_out, use_ws ? upd : nullptr, n4);

    // --- Pass 2: cone projection (staged volume, L3-warm from pass 1) ---
    const int blocks = (sino_size + 63) / 64;
    if (use_ws) {
        cone_project_seg_kernel<0><<<blocks, 256, 0, stream>>>(
            upd, nullptr,
            src_pos, det_center, det_u_vec, det_v_vec,
            du_p, dv_p, spacing_p, det_u_p, det_v_p, nsteps_p,
            sino, n_views, nx, ny, nz);
    } else {
        cone_project_seg_kernel<1><<<blocks, 256, 0, stream>>>(
            x, reco,
            src_pos, det_center, det_u_vec, det_v_vec,
            du_p, dv_p, spacing_p, det_u_p, det_v_p, nsteps_p,
            sino, n_views, nx, ny, nz);
    }
}